// Round 13
// baseline (915.965 us; speedup 1.0000x reference)
//
#include <hip/hip_runtime.h>

// KNNGraph bruteforce-blas, euclidean, k=16, include self.
// x: (N=4, M=8192, D=64) fp32. Output: int32 src[N*M*K] then dst[N*M*K].
//
// VALIDATED reference model (R9, absmax=0 — numerics FROZEN):
//   x2  = np.sum(x*x,-1): squares rounded per-element, FLOAT_pairwise_sum
//         n=64 NPY_SIMD path: 4 vec accs (vstep=4), serial blocks,
//         combine (r0+r1)+(r2+r3), double-hadd (S0+S1)+(S2+S3).
//   dot = np.einsum baseline-SSE: per-16 block REVERSED muladd chain
//         v_l = p0l+(p1l+(p2l+(p3l+v_l))), double-hadd (v0+v1)+(v2+v3).
//   d2  = fl(fl(x2j+x2c) - fl(2*dot)); stable ties by lower index.
//
// R17 lazy-threshold selection (800->631). R22 unroll-2 (631->586).
// R25 filtered rescore via RAW packed keys (total 832->656). BEST.
// R27/R28 occupancy levers NULL: grid x2 and waves_per_eu max=4 both left
//     OccupancyPercent ~21 — residency pinned at 2 waves/SIMD by actual
//     register allocation. P=16 reverted (its overhead cost 50us).
// R29: instruction-budget accounting: issue = 456 instr/pair; only ~210
//     are FMA+loads+keys+selection. The missing ~250 = the 128 staged
//     candidate floats round-tripping AGPRs (92 arch VGPR + ~164 acc =
//     256 budget at waves_per_eu min=2). FMA floor is 109us; ~280us is
//     register shuffle. FIX: waves_per_eu(1,1) -> 512-reg budget, q(128)
//     + staging(128) + sel(40) all fit in ARCH VGPRs, no accvgpr ops.
//     1 wave/SIMD; per-pair ILP (32 loads in flight ahead of 256-cycle
//     FMA chain) self-hides most latency. One-attribute change on the
//     proven R25 kernel; numerics/pi/rescore untouched.

#define MM 8192
#define NN 4
#define DD 64
#define KK 16
#define TK 20            // stage-A keep per chunk (16 + 4 safety margin)
#define TILE 64          // (LDS fallback path only)
#define NROWS (NN * MM)  // 32768
#define FB 10            // buffered-selection queue depth (R22)

typedef float f32x2 __attribute__((ext_vector_type(2)));

// numpy SIMD pairwise sum of squares (SSE baseline), n=64. FROZEN.
__global__ __launch_bounds__(256) void norms_np_kernel(
    const float* __restrict__ x, float* __restrict__ x2) {
#pragma clang fp contract(off)
  int r = blockIdx.x * 256 + threadIdx.x;
  if (r >= NROWS) return;
  const float4* p = (const float4*)(x + (size_t)r * DD);
  float s[DD];
#pragma unroll
  for (int i = 0; i < DD / 4; ++i) {
    float4 v = p[i];
    s[4 * i + 0] = v.x * v.x;
    s[4 * i + 1] = v.y * v.y;
    s[4 * i + 2] = v.z * v.z;
    s[4 * i + 3] = v.w * v.w;
  }
  float acc[4][4];
#pragma unroll
  for (int c = 0; c < 4; ++c)
#pragma unroll
    for (int l = 0; l < 4; ++l) acc[c][l] = s[4 * c + l];
#pragma unroll
  for (int b = 1; b < 4; ++b)
#pragma unroll
    for (int c = 0; c < 4; ++c)
#pragma unroll
      for (int l = 0; l < 4; ++l)
        acc[c][l] = acc[c][l] + s[16 * b + 4 * c + l];
  float S[4];
#pragma unroll
  for (int l = 0; l < 4; ++l)
    S[l] = (acc[0][l] + acc[1][l]) + (acc[2][l] + acc[3][l]);
  x2[r] = (S[0] + S[1]) + (S[2] + S[3]);
}

// Packed compare-swap: sA=min, sB=max (u32 => (quantized key, idx) lex).
#define PSTEP(sA, sB)                       \
  do {                                      \
    unsigned lo_ = min((sA), (sB));         \
    unsigned hi_ = max((sA), (sB));         \
    (sA) = lo_; (sB) = hi_;                 \
  } while (0)

#define PBUBBLE20(S)                                              \
  do {                                                            \
    PSTEP(S##18, S##19); PSTEP(S##17, S##18); PSTEP(S##16, S##17);\
    PSTEP(S##15, S##16); PSTEP(S##14, S##15); PSTEP(S##13, S##14);\
    PSTEP(S##12, S##13); PSTEP(S##11, S##12); PSTEP(S##10, S##11);\
    PSTEP(S##9,  S##10); PSTEP(S##8,  S##9);  PSTEP(S##7,  S##8); \
    PSTEP(S##6,  S##7);  PSTEP(S##5,  S##6);  PSTEP(S##4,  S##5); \
    PSTEP(S##3,  S##4);  PSTEP(S##2,  S##3);  PSTEP(S##1,  S##2); \
    PSTEP(S##0,  S##1);                                           \
  } while (0)

#define PDECL20(S)                                                          \
  unsigned S##0 = 0xFFFFFFFFu, S##1 = 0xFFFFFFFFu, S##2 = 0xFFFFFFFFu,      \
           S##3 = 0xFFFFFFFFu, S##4 = 0xFFFFFFFFu, S##5 = 0xFFFFFFFFu,      \
           S##6 = 0xFFFFFFFFu, S##7 = 0xFFFFFFFFu, S##8 = 0xFFFFFFFFu,      \
           S##9 = 0xFFFFFFFFu, S##10 = 0xFFFFFFFFu, S##11 = 0xFFFFFFFFu,    \
           S##12 = 0xFFFFFFFFu, S##13 = 0xFFFFFFFFu, S##14 = 0xFFFFFFFFu,   \
           S##15 = 0xFFFFFFFFu, S##16 = 0xFFFFFFFFu, S##17 = 0xFFFFFFFFu,   \
           S##18 = 0xFFFFFFFFu, S##19 = 0xFFFFFFFFu;

// R25: store RAW packed u32 (sorted ascending). Rescore recovers idx.
#define PSTORE20RAW(BASE, S)                                                \
  do {                                                                      \
    pi[(BASE) + 0]  = (int)S##0;  pi[(BASE) + 1]  = (int)S##1;              \
    pi[(BASE) + 2]  = (int)S##2;  pi[(BASE) + 3]  = (int)S##3;              \
    pi[(BASE) + 4]  = (int)S##4;  pi[(BASE) + 5]  = (int)S##5;              \
    pi[(BASE) + 6]  = (int)S##6;  pi[(BASE) + 7]  = (int)S##7;              \
    pi[(BASE) + 8]  = (int)S##8;  pi[(BASE) + 9]  = (int)S##9;              \
    pi[(BASE) + 10] = (int)S##10; pi[(BASE) + 11] = (int)S##11;             \
    pi[(BASE) + 12] = (int)S##12; pi[(BASE) + 13] = (int)S##13;             \
    pi[(BASE) + 14] = (int)S##14; pi[(BASE) + 15] = (int)S##15;             \
    pi[(BASE) + 16] = (int)S##16; pi[(BASE) + 17] = (int)S##17;             \
    pi[(BASE) + 18] = (int)S##18; pi[(BASE) + 19] = (int)S##19;             \
  } while (0)

// Fallback (index) store for the Q=1-LDS path.
#define PSTORE20(BASE, S, C0)                                               \
  do {                                                                      \
    pi[(BASE) + 0]  = (int)(S##0  & IMASK) + (C0);                          \
    pi[(BASE) + 1]  = (int)(S##1  & IMASK) + (C0);                          \
    pi[(BASE) + 2]  = (int)(S##2  & IMASK) + (C0);                          \
    pi[(BASE) + 3]  = (int)(S##3  & IMASK) + (C0);                          \
    pi[(BASE) + 4]  = (int)(S##4  & IMASK) + (C0);                          \
    pi[(BASE) + 5]  = (int)(S##5  & IMASK) + (C0);                          \
    pi[(BASE) + 6]  = (int)(S##6  & IMASK) + (C0);                          \
    pi[(BASE) + 7]  = (int)(S##7  & IMASK) + (C0);                          \
    pi[(BASE) + 8]  = (int)(S##8  & IMASK) + (C0);                          \
    pi[(BASE) + 9]  = (int)(S##9  & IMASK) + (C0);                          \
    pi[(BASE) + 10] = (int)(S##10 & IMASK) + (C0);                          \
    pi[(BASE) + 11] = (int)(S##11 & IMASK) + (C0);                          \
    pi[(BASE) + 12] = (int)(S##12 & IMASK) + (C0);                          \
    pi[(BASE) + 13] = (int)(S##13 & IMASK) + (C0);                          \
    pi[(BASE) + 14] = (int)(S##14 & IMASK) + (C0);                          \
    pi[(BASE) + 15] = (int)(S##15 & IMASK) + (C0);                          \
    pi[(BASE) + 16] = (int)(S##16 & IMASK) + (C0);                          \
    pi[(BASE) + 17] = (int)(S##17 & IMASK) + (C0);                          \
    pi[(BASE) + 18] = (int)(S##18 & IMASK) + (C0);                          \
    pi[(BASE) + 19] = (int)(S##19 & IMASK) + (C0);                          \
  } while (0)

// packed-fp32 dual-fma on one candidate float4 (v_pk_fma_f32 x2)
#define PK2(QF4, WLO, WHI, ACC0, ACC1)                             \
  do {                                                             \
    f32x2 qlo_ = {(QF4).x, (QF4).y};                               \
    f32x2 qhi_ = {(QF4).z, (QF4).w};                               \
    ACC0 = __builtin_elementwise_fma(qlo_, (WLO), ACC0);           \
    ACC1 = __builtin_elementwise_fma(qhi_, (WHI), ACC1);           \
  } while (0)

// Q=2 partial (R22 unroll-2), stores RAW packed u32 lists (R25).
// R29: waves_per_eu(1,1) — 512-reg budget so q + candidate staging live in
// ARCH VGPRs (no accvgpr round-trips). 1 wave/SIMD; deep per-pair ILP.
template <int P>
__global__ __launch_bounds__(256)
__attribute__((amdgpu_waves_per_eu(1, 1)))
void knn_partial2_kernel(
    const float* __restrict__ x, const float* __restrict__ x2,
    int* __restrict__ pi) {
  constexpr int IB = (P == 8) ? 10 : (P == 4) ? 11 : 12;
  constexpr unsigned IMASK = (1u << IB) - 1u;
  constexpr unsigned QMASK = ~IMASK;

  __shared__ unsigned lbufA[FB * 256];
  __shared__ unsigned lbufB[FB * 256];

  const int tid      = threadIdx.x;
  const int rb       = blockIdx.x / P;
  const int chunk    = blockIdx.x % P;
  const int base_row = rb * 512;
  const int b        = base_row >> 13;
  const int rowA     = base_row + tid;
  const int rowB     = rowA + 256;
  const int jA       = rowA & (MM - 1);
  const int jB       = jA + 256;

  const float* __restrict__ xb  = x + (size_t)b * MM * DD;
  const float* __restrict__ x2b = x2 + b * MM;

  const float4* qpA = (const float4*)(xb + (size_t)jA * DD);
  const float4* qpB = (const float4*)(xb + (size_t)jB * DD);
  float4 qa0 = qpA[0],  qa1 = qpA[1],  qa2 = qpA[2],  qa3 = qpA[3];
  float4 qa4 = qpA[4],  qa5 = qpA[5],  qa6 = qpA[6],  qa7 = qpA[7];
  float4 qa8 = qpA[8],  qa9 = qpA[9],  qa10 = qpA[10], qa11 = qpA[11];
  float4 qa12 = qpA[12], qa13 = qpA[13], qa14 = qpA[14], qa15 = qpA[15];
  float4 qb0 = qpB[0],  qb1 = qpB[1],  qb2 = qpB[2],  qb3 = qpB[3];
  float4 qb4 = qpB[4],  qb5 = qpB[5],  qb6 = qpB[6],  qb7 = qpB[7];
  float4 qb8 = qpB[8],  qb9 = qpB[9],  qb10 = qpB[10], qb11 = qpB[11];
  float4 qb12 = qpB[12], qb13 = qpB[13], qb14 = qpB[14], qb15 = qpB[15];

  PDECL20(sa)
  PDECL20(sb)
  int cA = 0, cB = 0;

#define FLUSHQ()                                                   \
  do {                                                             \
    _Pragma("unroll")                                              \
    for (int t_ = 0; t_ < FB; ++t_) {                              \
      if (t_ < cA) {                                               \
        unsigned pk_ = lbufA[t_ * 256 + tid];                      \
        sa19 = min(sa19, pk_);                                     \
        PBUBBLE20(sa);                                             \
      }                                                            \
      if (t_ < cB) {                                               \
        unsigned pk_ = lbufB[t_ * 256 + tid];                      \
        sb19 = min(sb19, pk_);                                     \
        PBUBBLE20(sb);                                             \
      }                                                            \
    }                                                              \
    cA = 0;                                                        \
    cB = 0;                                                        \
  } while (0)

  const int C  = MM / P;
  const int c0 = chunk * C;

#pragma unroll 1
  for (int c = c0; c < c0 + C; c += 2) {
    const float4* cp0 = (const float4*)(xb + (size_t)c * DD);        // unif
    const float4* cp1 = (const float4*)(xb + (size_t)(c + 1) * DD);  // unif
    float x2c0 = x2b[c];
    float x2c1 = x2b[c + 1];

    float4 u0 = cp0[0],  u1 = cp0[1],  u2 = cp0[2],  u3 = cp0[3];
    float4 u4 = cp0[4],  u5 = cp0[5],  u6 = cp0[6],  u7 = cp0[7];
    float4 u8 = cp0[8],  u9 = cp0[9],  u10 = cp0[10], u11 = cp0[11];
    float4 u12 = cp0[12], u13 = cp0[13], u14 = cp0[14], u15 = cp0[15];
    float4 t0 = cp1[0],  t1 = cp1[1],  t2 = cp1[2],  t3 = cp1[3];
    float4 t4 = cp1[4],  t5 = cp1[5],  t6 = cp1[6],  t7 = cp1[7];
    float4 t8 = cp1[8],  t9 = cp1[9],  t10 = cp1[10], t11 = cp1[11];
    float4 t12 = cp1[12], t13 = cp1[13], t14 = cp1[14], t15 = cp1[15];

    // ---- candidate c ----
    {
      f32x2 aA0 = {0.f, 0.f}, aA1 = {0.f, 0.f};
      f32x2 aB0 = {0.f, 0.f}, aB1 = {0.f, 0.f};
      {
        f32x2 wlo, whi;
#define USEW(W)  wlo = (f32x2){(W).x, (W).y}; whi = (f32x2){(W).z, (W).w}
        USEW(u0);  PK2(qa0,  wlo, whi, aA0, aA1); PK2(qb0,  wlo, whi, aB0, aB1);
        USEW(u1);  PK2(qa1,  wlo, whi, aA0, aA1); PK2(qb1,  wlo, whi, aB0, aB1);
        USEW(u2);  PK2(qa2,  wlo, whi, aA0, aA1); PK2(qb2,  wlo, whi, aB0, aB1);
        USEW(u3);  PK2(qa3,  wlo, whi, aA0, aA1); PK2(qb3,  wlo, whi, aB0, aB1);
        USEW(u4);  PK2(qa4,  wlo, whi, aA0, aA1); PK2(qb4,  wlo, whi, aB0, aB1);
        USEW(u5);  PK2(qa5,  wlo, whi, aA0, aA1); PK2(qb5,  wlo, whi, aB0, aB1);
        USEW(u6);  PK2(qa6,  wlo, whi, aA0, aA1); PK2(qb6,  wlo, whi, aB0, aB1);
        USEW(u7);  PK2(qa7,  wlo, whi, aA0, aA1); PK2(qb7,  wlo, whi, aB0, aB1);
        USEW(u8);  PK2(qa8,  wlo, whi, aA0, aA1); PK2(qb8,  wlo, whi, aB0, aB1);
        USEW(u9);  PK2(qa9,  wlo, whi, aA0, aA1); PK2(qb9,  wlo, whi, aB0, aB1);
        USEW(u10); PK2(qa10, wlo, whi, aA0, aA1); PK2(qb10, wlo, whi, aB0, aB1);
        USEW(u11); PK2(qa11, wlo, whi, aA0, aA1); PK2(qb11, wlo, whi, aB0, aB1);
        USEW(u12); PK2(qa12, wlo, whi, aA0, aA1); PK2(qb12, wlo, whi, aB0, aB1);
        USEW(u13); PK2(qa13, wlo, whi, aA0, aA1); PK2(qb13, wlo, whi, aB0, aB1);
        USEW(u14); PK2(qa14, wlo, whi, aA0, aA1); PK2(qb14, wlo, whi, aB0, aB1);
        USEW(u15); PK2(qa15, wlo, whi, aA0, aA1); PK2(qb15, wlo, whi, aB0, aB1);
      }
      f32x2 rA = aA0 + aA1;
      f32x2 rB = aB0 + aB1;
      float dotA = rA.x + rA.y;
      float dotB = rB.x + rB.y;
      float keyA = fmaf(-2.f, dotA, x2c0);
      float keyB = fmaf(-2.f, dotB, x2c0);

      int kiA = __float_as_int(keyA);
      unsigned monoA = (unsigned)kiA ^ ((unsigned)(kiA >> 31) | 0x80000000u);
      unsigned pkA = (monoA & QMASK) | (unsigned)(c - c0);
      if (pkA < sa19) { lbufA[cA * 256 + tid] = pkA; ++cA; }

      int kiB = __float_as_int(keyB);
      unsigned monoB = (unsigned)kiB ^ ((unsigned)(kiB >> 31) | 0x80000000u);
      unsigned pkB = (monoB & QMASK) | (unsigned)(c - c0);
      if (pkB < sb19) { lbufB[cB * 256 + tid] = pkB; ++cB; }
    }

    // ---- candidate c+1 ----
    {
      f32x2 aA0 = {0.f, 0.f}, aA1 = {0.f, 0.f};
      f32x2 aB0 = {0.f, 0.f}, aB1 = {0.f, 0.f};
      {
        f32x2 wlo, whi;
        USEW(t0);  PK2(qa0,  wlo, whi, aA0, aA1); PK2(qb0,  wlo, whi, aB0, aB1);
        USEW(t1);  PK2(qa1,  wlo, whi, aA0, aA1); PK2(qb1,  wlo, whi, aB0, aB1);
        USEW(t2);  PK2(qa2,  wlo, whi, aA0, aA1); PK2(qb2,  wlo, whi, aB0, aB1);
        USEW(t3);  PK2(qa3,  wlo, whi, aA0, aA1); PK2(qb3,  wlo, whi, aB0, aB1);
        USEW(t4);  PK2(qa4,  wlo, whi, aA0, aA1); PK2(qb4,  wlo, whi, aB0, aB1);
        USEW(t5);  PK2(qa5,  wlo, whi, aA0, aA1); PK2(qb5,  wlo, whi, aB0, aB1);
        USEW(t6);  PK2(qa6,  wlo, whi, aA0, aA1); PK2(qb6,  wlo, whi, aB0, aB1);
        USEW(t7);  PK2(qa7,  wlo, whi, aA0, aA1); PK2(qb7,  wlo, whi, aB0, aB1);
        USEW(t8);  PK2(qa8,  wlo, whi, aA0, aA1); PK2(qb8,  wlo, whi, aB0, aB1);
        USEW(t9);  PK2(qa9,  wlo, whi, aA0, aA1); PK2(qb9,  wlo, whi, aB0, aB1);
        USEW(t10); PK2(qa10, wlo, whi, aA0, aA1); PK2(qb10, wlo, whi, aB0, aB1);
        USEW(t11); PK2(qa11, wlo, whi, aA0, aA1); PK2(qb11, wlo, whi, aB0, aB1);
        USEW(t12); PK2(qa12, wlo, whi, aA0, aA1); PK2(qb12, wlo, whi, aB0, aB1);
        USEW(t13); PK2(qa13, wlo, whi, aA0, aA1); PK2(qb13, wlo, whi, aB0, aB1);
        USEW(t14); PK2(qa14, wlo, whi, aA0, aA1); PK2(qb14, wlo, whi, aB0, aB1);
        USEW(t15); PK2(qa15, wlo, whi, aA0, aA1); PK2(qb15, wlo, whi, aB0, aB1);
#undef USEW
      }
      f32x2 rA = aA0 + aA1;
      f32x2 rB = aB0 + aB1;
      float dotA = rA.x + rA.y;
      float dotB = rB.x + rB.y;
      float keyA = fmaf(-2.f, dotA, x2c1);
      float keyB = fmaf(-2.f, dotB, x2c1);

      int kiA = __float_as_int(keyA);
      unsigned monoA = (unsigned)kiA ^ ((unsigned)(kiA >> 31) | 0x80000000u);
      unsigned pkA = (monoA & QMASK) | (unsigned)(c + 1 - c0);
      if (pkA < sa19) { lbufA[cA * 256 + tid] = pkA; ++cA; }

      int kiB = __float_as_int(keyB);
      unsigned monoB = (unsigned)kiB ^ ((unsigned)(kiB >> 31) | 0x80000000u);
      unsigned pkB = (monoB & QMASK) | (unsigned)(c + 1 - c0);
      if (pkB < sb19) { lbufB[cB * 256 + tid] = pkB; ++cB; }
    }

    if (__any((cA | cB) >= FB - 2)) FLUSHQ();
  }

  FLUSHQ();  // final drain
#undef FLUSHQ

  size_t baseA = ((size_t)rowA * P + chunk) * TK;
  size_t baseB = ((size_t)rowB * P + chunk) * TK;
  PSTORE20RAW(baseA, sa);
  PSTORE20RAW(baseB, sb);
}

// Q=1 packed partial (LDS path) — workspace fallback only (stores idx).
template <int P>
__global__ __launch_bounds__(256)
__attribute__((amdgpu_waves_per_eu(2, 2)))
void knn_partial_q1_kernel(
    const float* __restrict__ x, const float* __restrict__ x2,
    int* __restrict__ pi) {
  constexpr int IB = (P == 8) ? 10 : (P == 4) ? 11 : (P == 2) ? 12 : 13;
  constexpr unsigned IMASK = (1u << IB) - 1u;
  constexpr unsigned QMASK = ~IMASK;

  __shared__ float tile[TILE * DD];
  __shared__ float x2t[TILE];

  const int tid   = threadIdx.x;
  const int rb    = blockIdx.x / P;
  const int chunk = blockIdx.x % P;
  const int b     = rb >> 5;
  const int row   = rb * 256 + tid;
  const int j     = row - b * MM;

  const float* __restrict__ xb  = x + (size_t)b * MM * DD;
  const float* __restrict__ x2b = x2 + b * MM;

  const float4* qp = (const float4*)(xb + (size_t)j * DD);
  float4 q0 = qp[0],  q1 = qp[1],  q2 = qp[2],  q3 = qp[3];
  float4 q4 = qp[4],  q5 = qp[5],  q6 = qp[6],  q7 = qp[7];
  float4 q8 = qp[8],  q9 = qp[9],  q10 = qp[10], q11 = qp[11];
  float4 q12 = qp[12], q13 = qp[13], q14 = qp[14], q15 = qp[15];

  PDECL20(s)

  const int C  = MM / P;
  const int c0 = chunk * C;

  for (int ts = c0; ts < c0 + C; ts += TILE) {
    __syncthreads();
    {
      const float4* gsrc = (const float4*)(xb + (size_t)ts * DD);
      float4* lds4 = (float4*)tile;
#pragma unroll
      for (int u = 0; u < 4; ++u) lds4[tid + 256 * u] = gsrc[tid + 256 * u];
      if (tid < TILE / 4)
        ((float4*)x2t)[tid] = ((const float4*)(x2b + ts))[tid];
    }
    __syncthreads();

#pragma unroll 2
    for (int t = 0; t < TILE; ++t) {
      const float4* cp = (const float4*)(tile + t * DD);
      f32x2 a0 = {0.f, 0.f}, a1 = {0.f, 0.f};
      {
        float4 w;
        f32x2 wlo, whi;
#define LOADW(I)  w = cp[I]; wlo = (f32x2){w.x, w.y}; whi = (f32x2){w.z, w.w}
        LOADW(0);  PK2(q0,  wlo, whi, a0, a1);
        LOADW(1);  PK2(q1,  wlo, whi, a0, a1);
        LOADW(2);  PK2(q2,  wlo, whi, a0, a1);
        LOADW(3);  PK2(q3,  wlo, whi, a0, a1);
        LOADW(4);  PK2(q4,  wlo, whi, a0, a1);
        LOADW(5);  PK2(q5,  wlo, whi, a0, a1);
        LOADW(6);  PK2(q6,  wlo, whi, a0, a1);
        LOADW(7);  PK2(q7,  wlo, whi, a0, a1);
        LOADW(8);  PK2(q8,  wlo, whi, a0, a1);
        LOADW(9);  PK2(q9,  wlo, whi, a0, a1);
        LOADW(10); PK2(q10, wlo, whi, a0, a1);
        LOADW(11); PK2(q11, wlo, whi, a0, a1);
        LOADW(12); PK2(q12, wlo, whi, a0, a1);
        LOADW(13); PK2(q13, wlo, whi, a0, a1);
        LOADW(14); PK2(q14, wlo, whi, a0, a1);
        LOADW(15); PK2(q15, wlo, whi, a0, a1);
#undef LOADW
      }
      f32x2 rr = a0 + a1;
      float dot = rr.x + rr.y;
      float key = fmaf(-2.f, dot, x2t[t]);

      int ki = __float_as_int(key);
      unsigned mono = (unsigned)ki ^ ((unsigned)(ki >> 31) | 0x80000000u);
      unsigned pk = (mono & QMASK) | (unsigned)(ts - c0 + t);
      s19 = min(s19, pk);
      PBUBBLE20(s);
    }
  }

  size_t base = ((size_t)row * P + chunk) * TK;
  PSTORE20(base, s, c0);
}

// FROZEN-numerics einsum block: per-product rounding then reversed adds.
#define EBLK(QA, QB, QC, QD, W0, W1, W2, W3)                                  \
  do {                                                                        \
    v0 = (QA).x * (W0).x +                                                    \
         ((QB).x * (W1).x + ((QC).x * (W2).x + ((QD).x * (W3).x + v0)));      \
    v1 = (QA).y * (W0).y +                                                    \
         ((QB).y * (W1).y + ((QC).y * (W2).y + ((QD).y * (W3).y + v1)));      \
    v2 = (QA).z * (W0).z +                                                    \
         ((QB).z * (W1).z + ((QC).z * (W2).z + ((QD).z * (W3).z + v2)));      \
    v3 = (QA).w * (W0).w +                                                    \
         ((QB).w * (W1).w + ((QC).w * (W2).w + ((QD).w * (W3).w + v3)));      \
  } while (0)

// Lexicographic (d2, idx) compare-swap (strict: stable).
#define LBSTEP(dA, iA, dB, iB)                                     \
  do {                                                             \
    bool s_ = ((dB) < (dA)) || ((dB) == (dA) && (iB) < (iA));      \
    float tl_ = s_ ? (dB) : (dA);                                  \
    float th_ = s_ ? (dA) : (dB);                                  \
    int   jl_ = s_ ? (iB) : (iA);                                  \
    int   jh_ = s_ ? (iA) : (iB);                                  \
    (dA) = tl_; (dB) = th_; (iA) = jl_; (iB) = jh_;                \
  } while (0)

// Exact rescore of one candidate + insertion (shared by rescore kernels).
#define RESCORE_ONE(C_)                                                     \
  {                                                                         \
    int c = (C_);                                                           \
    const float4* pp = (const float4*)(xb + (size_t)c * DD);                \
    float v0 = 0.f, v1 = 0.f, v2 = 0.f, v3 = 0.f;                           \
    {                                                                       \
      float4 w0 = pp[0], w1 = pp[1], w2 = pp[2], w3 = pp[3];                \
      EBLK(q0, q1, q2, q3, w0, w1, w2, w3);                                 \
    }                                                                       \
    {                                                                       \
      float4 w0 = pp[4], w1 = pp[5], w2 = pp[6], w3 = pp[7];                \
      EBLK(q4, q5, q6, q7, w0, w1, w2, w3);                                 \
    }                                                                       \
    {                                                                       \
      float4 w0 = pp[8], w1 = pp[9], w2 = pp[10], w3 = pp[11];              \
      EBLK(q8, q9, q10, q11, w0, w1, w2, w3);                               \
    }                                                                       \
    {                                                                       \
      float4 w0 = pp[12], w1 = pp[13], w2 = pp[14], w3 = pp[15];            \
      EBLK(q12, q13, q14, q15, w0, w1, w2, w3);                             \
    }                                                                       \
    float dotf = (v0 + v1) + (v2 + v3);                                     \
    float s  = x2j + x2[b * MM + c];                                        \
    float tm = 2.0f * dotf;                                                 \
    float d2 = s - tm;                                                      \
    bool lt = (d2 < e15) || (d2 == e15 && c < n15);                         \
    e15 = lt ? d2 : e15;                                                    \
    n15 = lt ? c : n15;                                                     \
    LBSTEP(e14, n14, e15, n15); LBSTEP(e13, n13, e14, n14);                 \
    LBSTEP(e12, n12, e13, n13); LBSTEP(e11, n11, e12, n12);                 \
    LBSTEP(e10, n10, e11, n11); LBSTEP(e9,  n9,  e10, n10);                 \
    LBSTEP(e8,  n8,  e9,  n9);  LBSTEP(e7,  n7,  e8,  n8);                  \
    LBSTEP(e6,  n6,  e7,  n7);  LBSTEP(e5,  n5,  e6,  n6);                  \
    LBSTEP(e4,  n4,  e5,  n5);  LBSTEP(e3,  n3,  e4,  n4);                  \
    LBSTEP(e2,  n2,  e3,  n3);  LBSTEP(e1,  n1,  e2,  n2);                  \
    LBSTEP(e0,  n0,  e1,  n1);                                              \
  }

// Publish per-sub sorted list + 8-way final merge (shared epilogue).
#define PUBLISH_AND_MERGE8()                                                \
  {                                                                         \
    ls[sub][0][lane]  = make_uint2(MONO(e0),  (unsigned)n0);                \
    ls[sub][1][lane]  = make_uint2(MONO(e1),  (unsigned)n1);                \
    ls[sub][2][lane]  = make_uint2(MONO(e2),  (unsigned)n2);                \
    ls[sub][3][lane]  = make_uint2(MONO(e3),  (unsigned)n3);                \
    ls[sub][4][lane]  = make_uint2(MONO(e4),  (unsigned)n4);                \
    ls[sub][5][lane]  = make_uint2(MONO(e5),  (unsigned)n5);                \
    ls[sub][6][lane]  = make_uint2(MONO(e6),  (unsigned)n6);                \
    ls[sub][7][lane]  = make_uint2(MONO(e7),  (unsigned)n7);                \
    ls[sub][8][lane]  = make_uint2(MONO(e8),  (unsigned)n8);                \
    ls[sub][9][lane]  = make_uint2(MONO(e9),  (unsigned)n9);                \
    ls[sub][10][lane] = make_uint2(MONO(e10), (unsigned)n10);               \
    ls[sub][11][lane] = make_uint2(MONO(e11), (unsigned)n11);               \
    ls[sub][12][lane] = make_uint2(MONO(e12), (unsigned)n12);               \
    ls[sub][13][lane] = make_uint2(MONO(e13), (unsigned)n13);               \
    ls[sub][14][lane] = make_uint2(MONO(e14), (unsigned)n14);               \
    ls[sub][15][lane] = make_uint2(MONO(e15), (unsigned)n15);               \
    __syncthreads();                                                        \
    if (sub == 0) {                                                         \
      uint2 c0v = ls[0][0][lane], c1v = ls[1][0][lane];                     \
      uint2 c2v = ls[2][0][lane], c3v = ls[3][0][lane];                     \
      uint2 c4v = ls[4][0][lane], c5v = ls[5][0][lane];                     \
      uint2 c6v = ls[6][0][lane], c7v = ls[7][0][lane];                     \
      int h0 = 1, h1 = 1, h2 = 1, h3 = 1, h4 = 1, h5 = 1, h6 = 1, h7 = 1;   \
      const uint2 SENT = make_uint2(0xFFFFFFFFu, 0x7FFFFFFFu);              \
      for (int out = 0; out < KK; ++out) {                                  \
        bool l01 = LESS2(c0v, c1v);                                         \
        uint2 m01 = l01 ? c0v : c1v; int w01 = l01 ? 0 : 1;                 \
        bool l23 = LESS2(c2v, c3v);                                         \
        uint2 m23 = l23 ? c2v : c3v; int w23 = l23 ? 2 : 3;                 \
        bool l45 = LESS2(c4v, c5v);                                         \
        uint2 m45 = l45 ? c4v : c5v; int w45 = l45 ? 4 : 5;                 \
        bool l67 = LESS2(c6v, c7v);                                         \
        uint2 m67 = l67 ? c6v : c7v; int w67 = l67 ? 6 : 7;                 \
        bool la = LESS2(m01, m23);                                          \
        uint2 ma = la ? m01 : m23; int wa = la ? w01 : w23;                 \
        bool lb = LESS2(m45, m67);                                          \
        uint2 mb = lb ? m45 : m67; int wb = lb ? w45 : w67;                 \
        bool lf = LESS2(ma, mb);                                            \
        uint2 mv = lf ? ma : mb; int wf = lf ? wa : wb;                     \
        src[(size_t)r * KK + out] = b * MM + (int)mv.y;                     \
        dst[(size_t)r * KK + out] = r;                                      \
        if (wf == 0)      { c0v = (h0 < 16) ? ls[0][h0][lane] : SENT; ++h0; }\
        else if (wf == 1) { c1v = (h1 < 16) ? ls[1][h1][lane] : SENT; ++h1; }\
        else if (wf == 2) { c2v = (h2 < 16) ? ls[2][h2][lane] : SENT; ++h2; }\
        else if (wf == 3) { c3v = (h3 < 16) ? ls[3][h3][lane] : SENT; ++h3; }\
        else if (wf == 4) { c4v = (h4 < 16) ? ls[4][h4][lane] : SENT; ++h4; }\
        else if (wf == 5) { c5v = (h5 < 16) ? ls[5][h5][lane] : SENT; ++h5; }\
        else if (wf == 6) { c6v = (h6 < 16) ? ls[6][h6][lane] : SENT; ++h6; }\
        else              { c7v = (h7 < 16) ? ls[7][h7][lane] : SENT; ++h7; }\
      }                                                                     \
    }                                                                       \
  }

#define MONO(F) ({ int k_ = __float_as_int(F); \
                   (unsigned)k_ ^ ((unsigned)(k_ >> 31) | 0x80000000u); })
#define LESS2(A, B) ((A).x < (B).x || ((A).x == (B).x && (A).y < (B).y))

// R25 filtered rescore (P=8/4 path): 8 sorted chunk-lists, 8 subs.
template <int P>
__global__ __launch_bounds__(256) void knn_rescore8f_kernel(
    const float* __restrict__ x, const float* __restrict__ x2,
    const int* __restrict__ pi,
    int* __restrict__ src, int* __restrict__ dst) {
#pragma clang fp contract(off)
  constexpr int IB = (P == 8) ? 10 : 11;
  constexpr unsigned IMASK = (1u << IB) - 1u;
  constexpr unsigned QMASK = ~IMASK;
  constexpr int CAND = P * TK;
  constexpr int LPT  = CAND / 8;
  constexpr int CC   = MM / P;

  __shared__ unsigned lk[8][LPT][32];
  __shared__ uint2 ls[8][16][32];
  __shared__ unsigned thr[32];

  const int tid  = threadIdx.x;
  const int lane = tid & 31;
  const int sub  = tid >> 5;
  const int r    = blockIdx.x * 32 + lane;
  const int b    = r >> 13;
  const int j    = r & (MM - 1);
  const float* __restrict__ xb = x + (size_t)b * MM * DD;
  const float x2j = x2[r];

  const float4* qp = (const float4*)(xb + (size_t)j * DD);
  float4 q0 = qp[0],  q1 = qp[1],  q2 = qp[2],  q3 = qp[3];
  float4 q4 = qp[4],  q5 = qp[5],  q6 = qp[6],  q7 = qp[7];
  float4 q8 = qp[8],  q9 = qp[9],  q10 = qp[10], q11 = qp[11];
  float4 q12 = qp[12], q13 = qp[13], q14 = qp[14], q15 = qp[15];

  {
    const uint2* pp2 =
        (const uint2*)((const unsigned*)pi + (size_t)r * CAND + sub * LPT);
#pragma unroll
    for (int i = 0; i < LPT / 2; ++i) {
      uint2 v = pp2[i];
      lk[sub][2 * i][lane]     = v.x;
      lk[sub][2 * i + 1][lane] = v.y;
    }
  }
  __syncthreads();

  if (sub == 0) {
    unsigned c0v = lk[0][0][lane], c1v = lk[1][0][lane];
    unsigned c2v = lk[2][0][lane], c3v = lk[3][0][lane];
    unsigned c4v = lk[4][0][lane], c5v = lk[5][0][lane];
    unsigned c6v = lk[6][0][lane], c7v = lk[7][0][lane];
    int h0 = 1, h1 = 1, h2 = 1, h3 = 1, h4 = 1, h5 = 1, h6 = 1, h7 = 1;
    unsigned P16 = 0;
#pragma unroll 1
    for (int out = 0; out < 16; ++out) {
      bool l01 = c0v < c1v; unsigned m01 = l01 ? c0v : c1v; int w01 = l01 ? 0 : 1;
      bool l23 = c2v < c3v; unsigned m23 = l23 ? c2v : c3v; int w23 = l23 ? 2 : 3;
      bool l45 = c4v < c5v; unsigned m45 = l45 ? c4v : c5v; int w45 = l45 ? 4 : 5;
      bool l67 = c6v < c7v; unsigned m67 = l67 ? c6v : c7v; int w67 = l67 ? 6 : 7;
      bool la = m01 < m23; unsigned ma = la ? m01 : m23; int wa = la ? w01 : w23;
      bool lb = m45 < m67; unsigned mb = lb ? m45 : m67; int wb = lb ? w45 : w67;
      bool lf = ma < mb; unsigned mv = lf ? ma : mb; int wf = lf ? wa : wb;
      P16 = mv;
      if (wf == 0)      { c0v = (h0 < LPT) ? lk[0][h0][lane] : 0xFFFFFFFFu; ++h0; }
      else if (wf == 1) { c1v = (h1 < LPT) ? lk[1][h1][lane] : 0xFFFFFFFFu; ++h1; }
      else if (wf == 2) { c2v = (h2 < LPT) ? lk[2][h2][lane] : 0xFFFFFFFFu; ++h2; }
      else if (wf == 3) { c3v = (h3 < LPT) ? lk[3][h3][lane] : 0xFFFFFFFFu; ++h3; }
      else if (wf == 4) { c4v = (h4 < LPT) ? lk[4][h4][lane] : 0xFFFFFFFFu; ++h4; }
      else if (wf == 5) { c5v = (h5 < LPT) ? lk[5][h5][lane] : 0xFFFFFFFFu; ++h5; }
      else if (wf == 6) { c6v = (h6 < LPT) ? lk[6][h6][lane] : 0xFFFFFFFFu; ++h6; }
      else              { c7v = (h7 < LPT) ? lk[7][h7][lane] : 0xFFFFFFFFu; ++h7; }
    }
    thr[lane] = ((P16 & QMASK) + (1u << IB)) | IMASK;
  }
  __syncthreads();
  const unsigned T = thr[lane];

  const float INF = __builtin_inff();
  float e0 = INF, e1 = INF, e2 = INF, e3 = INF, e4 = INF, e5 = INF,
        e6 = INF, e7 = INF, e8 = INF, e9 = INF, e10 = INF, e11 = INF,
        e12 = INF, e13 = INF, e14 = INF, e15 = INF;
  int n0 = 0x7fffffff, n1 = 0x7fffffff, n2 = 0x7fffffff, n3 = 0x7fffffff,
      n4 = 0x7fffffff, n5 = 0x7fffffff, n6 = 0x7fffffff, n7 = 0x7fffffff,
      n8 = 0x7fffffff, n9 = 0x7fffffff, n10 = 0x7fffffff, n11 = 0x7fffffff,
      n12 = 0x7fffffff, n13 = 0x7fffffff, n14 = 0x7fffffff, n15 = 0x7fffffff;

#pragma unroll 1
  for (int t = 0; t < LPT; ++t) {
    unsigned pk = lk[sub][t][lane];
    if (__all((int)(pk > T))) break;
    if (pk <= T) {
      int ent = sub * LPT + t;
      int chunk = ent / TK;
      RESCORE_ONE((int)(pk & IMASK) + chunk * CC)
    }
  }

  PUBLISH_AND_MERGE8()
}

// Index-based rescore (fallback path, pi = plain indices).
template <int P>
__global__ __launch_bounds__(256) void knn_rescore8_kernel(
    const float* __restrict__ x, const float* __restrict__ x2,
    const int* __restrict__ pi,
    int* __restrict__ src, int* __restrict__ dst) {
#pragma clang fp contract(off)
  constexpr int CAND = P * TK;
  constexpr int LPT  = CAND / 8;
  __shared__ uint2 ls[8][16][32];

  const int tid  = threadIdx.x;
  const int lane = tid & 31;
  const int sub  = tid >> 5;
  const int r    = blockIdx.x * 32 + lane;
  const int b    = r >> 13;
  const int j    = r & (MM - 1);
  const float* __restrict__ xb = x + (size_t)b * MM * DD;
  const float x2j = x2[r];

  const float4* qp = (const float4*)(xb + (size_t)j * DD);
  float4 q0 = qp[0],  q1 = qp[1],  q2 = qp[2],  q3 = qp[3];
  float4 q4 = qp[4],  q5 = qp[5],  q6 = qp[6],  q7 = qp[7];
  float4 q8 = qp[8],  q9 = qp[9],  q10 = qp[10], q11 = qp[11];
  float4 q12 = qp[12], q13 = qp[13], q14 = qp[14], q15 = qp[15];

  const float INF = __builtin_inff();
  float e0 = INF, e1 = INF, e2 = INF, e3 = INF, e4 = INF, e5 = INF,
        e6 = INF, e7 = INF, e8 = INF, e9 = INF, e10 = INF, e11 = INF,
        e12 = INF, e13 = INF, e14 = INF, e15 = INF;
  int n0 = 0x7fffffff, n1 = 0x7fffffff, n2 = 0x7fffffff, n3 = 0x7fffffff,
      n4 = 0x7fffffff, n5 = 0x7fffffff, n6 = 0x7fffffff, n7 = 0x7fffffff,
      n8 = 0x7fffffff, n9 = 0x7fffffff, n10 = 0x7fffffff, n11 = 0x7fffffff,
      n12 = 0x7fffffff, n13 = 0x7fffffff, n14 = 0x7fffffff, n15 = 0x7fffffff;

  size_t base = (size_t)r * CAND + (size_t)sub * LPT;

  for (int t = 0; t < LPT; ++t) {
    RESCORE_ONE(pi[base + t])
  }

  PUBLISH_AND_MERGE8()
}

extern "C" void kernel_launch(void* const* d_in, const int* in_sizes, int n_in,
                              void* d_out, int out_size, void* d_ws, size_t ws_size,
                              hipStream_t stream) {
  const float* x = (const float*)d_in[0];
  int* out = (int*)d_out;

  char* ws = (char*)d_ws;
  float* x2 = (float*)ws;
  int*   pi = (int*)(ws + (size_t)NROWS * sizeof(float));
  int* src = out;
  int* dst = out + (size_t)NROWS * KK;

  auto need = [](int P) {
    return (size_t)NROWS * sizeof(float) +
           (size_t)NROWS * P * TK * sizeof(int);
  };

  norms_np_kernel<<<NROWS / 256, 256, 0, stream>>>(x, x2);

  if (ws_size >= need(8)) {
    // R29: R25 pipeline, partial with waves_per_eu(1,1) (512-reg budget).
    knn_partial2_kernel<8><<<(NROWS / 512) * 8, 256, 0, stream>>>(x, x2, pi);
    knn_rescore8f_kernel<8><<<NROWS / 32, 256, 0, stream>>>(x, x2, pi, src, dst);
  } else if (ws_size >= need(4)) {
    knn_partial2_kernel<4><<<(NROWS / 512) * 4, 256, 0, stream>>>(x, x2, pi);
    knn_rescore8f_kernel<4><<<NROWS / 32, 256, 0, stream>>>(x, x2, pi, src, dst);
  } else if (ws_size >= need(2)) {
    knn_partial_q1_kernel<2><<<(NROWS / 256) * 2, 256, 0, stream>>>(x, x2, pi);
    knn_rescore8_kernel<2><<<NROWS / 32, 256, 0, stream>>>(x, x2, pi, src, dst);
  } else {
    knn_partial_q1_kernel<1><<<(NROWS / 256) * 1, 256, 0, stream>>>(x, x2, pi);
    knn_rescore8_kernel<1><<<NROWS / 32, 256, 0, stream>>>(x, x2, pi, src, dst);
  }
}

// Round 14
// 654.439 us; speedup vs baseline: 1.3996x; 1.3996x over previous
//
#include <hip/hip_runtime.h>

// KNNGraph bruteforce-blas, euclidean, k=16, include self.
// x: (N=4, M=8192, D=64) fp32. Output: int32 src[N*M*K] then dst[N*M*K].
//
// VALIDATED reference model (R9, absmax=0 — numerics FROZEN):
//   x2  = np.sum(x*x,-1): squares rounded per-element, FLOAT_pairwise_sum
//         n=64 NPY_SIMD path: 4 vec accs (vstep=4), serial blocks,
//         combine (r0+r1)+(r2+r3), double-hadd (S0+S1)+(S2+S3).
//   dot = np.einsum baseline-SSE: per-16 block REVERSED muladd chain
//         v_l = p0l+(p1l+(p2l+(p3l+v_l))), double-hadd (v0+v1)+(v2+v3).
//   d2  = fl(fl(x2j+x2c) - fl(2*dot)); stable ties by lower index.
//
// R17 lazy-threshold selection (800->631). R22 unroll-2 (631->586).
// R25 filtered rescore via RAW packed keys (total 832->656). BEST.
// R26-R29 register/occupancy levers ALL NULL or regressions (allocator
//     ignores attribute budgets: R29 gave VGPR 132 not 320, occ 11%).
// R30: the ~250 unexplained issue-cycles/pair = operand-marshalling movs.
//     HIP float4 is a STRUCT; building f32x2 from {w.x,w.y} lowers to
//     v_mov pairs (~128/pair). Fix: native ext_vector_type(4) fragments +
//     __builtin_shufflevector halves -> sub-register aliasing, zero movs.
//     Same loads, same FMA order -> numerics/pi byte-identical, absmax 0.
//     Partial back at proven waves_per_eu(2,2).

#define MM 8192
#define NN 4
#define DD 64
#define KK 16
#define TK 20            // stage-A keep per chunk (16 + 4 safety margin)
#define TILE 64          // (LDS fallback path only)
#define NROWS (NN * MM)  // 32768
#define FB 10            // buffered-selection queue depth (R22)

typedef float f32x2 __attribute__((ext_vector_type(2)));
typedef float f32x4 __attribute__((ext_vector_type(4)));

// numpy SIMD pairwise sum of squares (SSE baseline), n=64. FROZEN.
__global__ __launch_bounds__(256) void norms_np_kernel(
    const float* __restrict__ x, float* __restrict__ x2) {
#pragma clang fp contract(off)
  int r = blockIdx.x * 256 + threadIdx.x;
  if (r >= NROWS) return;
  const float4* p = (const float4*)(x + (size_t)r * DD);
  float s[DD];
#pragma unroll
  for (int i = 0; i < DD / 4; ++i) {
    float4 v = p[i];
    s[4 * i + 0] = v.x * v.x;
    s[4 * i + 1] = v.y * v.y;
    s[4 * i + 2] = v.z * v.z;
    s[4 * i + 3] = v.w * v.w;
  }
  float acc[4][4];
#pragma unroll
  for (int c = 0; c < 4; ++c)
#pragma unroll
    for (int l = 0; l < 4; ++l) acc[c][l] = s[4 * c + l];
#pragma unroll
  for (int b = 1; b < 4; ++b)
#pragma unroll
    for (int c = 0; c < 4; ++c)
#pragma unroll
      for (int l = 0; l < 4; ++l)
        acc[c][l] = acc[c][l] + s[16 * b + 4 * c + l];
  float S[4];
#pragma unroll
  for (int l = 0; l < 4; ++l)
    S[l] = (acc[0][l] + acc[1][l]) + (acc[2][l] + acc[3][l]);
  x2[r] = (S[0] + S[1]) + (S[2] + S[3]);
}

// Packed compare-swap: sA=min, sB=max (u32 => (quantized key, idx) lex).
#define PSTEP(sA, sB)                       \
  do {                                      \
    unsigned lo_ = min((sA), (sB));         \
    unsigned hi_ = max((sA), (sB));         \
    (sA) = lo_; (sB) = hi_;                 \
  } while (0)

#define PBUBBLE20(S)                                              \
  do {                                                            \
    PSTEP(S##18, S##19); PSTEP(S##17, S##18); PSTEP(S##16, S##17);\
    PSTEP(S##15, S##16); PSTEP(S##14, S##15); PSTEP(S##13, S##14);\
    PSTEP(S##12, S##13); PSTEP(S##11, S##12); PSTEP(S##10, S##11);\
    PSTEP(S##9,  S##10); PSTEP(S##8,  S##9);  PSTEP(S##7,  S##8); \
    PSTEP(S##6,  S##7);  PSTEP(S##5,  S##6);  PSTEP(S##4,  S##5); \
    PSTEP(S##3,  S##4);  PSTEP(S##2,  S##3);  PSTEP(S##1,  S##2); \
    PSTEP(S##0,  S##1);                                           \
  } while (0)

#define PDECL20(S)                                                          \
  unsigned S##0 = 0xFFFFFFFFu, S##1 = 0xFFFFFFFFu, S##2 = 0xFFFFFFFFu,      \
           S##3 = 0xFFFFFFFFu, S##4 = 0xFFFFFFFFu, S##5 = 0xFFFFFFFFu,      \
           S##6 = 0xFFFFFFFFu, S##7 = 0xFFFFFFFFu, S##8 = 0xFFFFFFFFu,      \
           S##9 = 0xFFFFFFFFu, S##10 = 0xFFFFFFFFu, S##11 = 0xFFFFFFFFu,    \
           S##12 = 0xFFFFFFFFu, S##13 = 0xFFFFFFFFu, S##14 = 0xFFFFFFFFu,   \
           S##15 = 0xFFFFFFFFu, S##16 = 0xFFFFFFFFu, S##17 = 0xFFFFFFFFu,   \
           S##18 = 0xFFFFFFFFu, S##19 = 0xFFFFFFFFu;

// R25: store RAW packed u32 (sorted ascending). Rescore recovers idx.
#define PSTORE20RAW(BASE, S)                                                \
  do {                                                                      \
    pi[(BASE) + 0]  = (int)S##0;  pi[(BASE) + 1]  = (int)S##1;              \
    pi[(BASE) + 2]  = (int)S##2;  pi[(BASE) + 3]  = (int)S##3;              \
    pi[(BASE) + 4]  = (int)S##4;  pi[(BASE) + 5]  = (int)S##5;              \
    pi[(BASE) + 6]  = (int)S##6;  pi[(BASE) + 7]  = (int)S##7;              \
    pi[(BASE) + 8]  = (int)S##8;  pi[(BASE) + 9]  = (int)S##9;              \
    pi[(BASE) + 10] = (int)S##10; pi[(BASE) + 11] = (int)S##11;             \
    pi[(BASE) + 12] = (int)S##12; pi[(BASE) + 13] = (int)S##13;             \
    pi[(BASE) + 14] = (int)S##14; pi[(BASE) + 15] = (int)S##15;             \
    pi[(BASE) + 16] = (int)S##16; pi[(BASE) + 17] = (int)S##17;             \
    pi[(BASE) + 18] = (int)S##18; pi[(BASE) + 19] = (int)S##19;             \
  } while (0)

// Fallback (index) store for the Q=1-LDS path.
#define PSTORE20(BASE, S, C0)                                               \
  do {                                                                      \
    pi[(BASE) + 0]  = (int)(S##0  & IMASK) + (C0);                          \
    pi[(BASE) + 1]  = (int)(S##1  & IMASK) + (C0);                          \
    pi[(BASE) + 2]  = (int)(S##2  & IMASK) + (C0);                          \
    pi[(BASE) + 3]  = (int)(S##3  & IMASK) + (C0);                          \
    pi[(BASE) + 4]  = (int)(S##4  & IMASK) + (C0);                          \
    pi[(BASE) + 5]  = (int)(S##5  & IMASK) + (C0);                          \
    pi[(BASE) + 6]  = (int)(S##6  & IMASK) + (C0);                          \
    pi[(BASE) + 7]  = (int)(S##7  & IMASK) + (C0);                          \
    pi[(BASE) + 8]  = (int)(S##8  & IMASK) + (C0);                          \
    pi[(BASE) + 9]  = (int)(S##9  & IMASK) + (C0);                          \
    pi[(BASE) + 10] = (int)(S##10 & IMASK) + (C0);                          \
    pi[(BASE) + 11] = (int)(S##11 & IMASK) + (C0);                          \
    pi[(BASE) + 12] = (int)(S##12 & IMASK) + (C0);                          \
    pi[(BASE) + 13] = (int)(S##13 & IMASK) + (C0);                          \
    pi[(BASE) + 14] = (int)(S##14 & IMASK) + (C0);                          \
    pi[(BASE) + 15] = (int)(S##15 & IMASK) + (C0);                          \
    pi[(BASE) + 16] = (int)(S##16 & IMASK) + (C0);                          \
    pi[(BASE) + 17] = (int)(S##17 & IMASK) + (C0);                          \
    pi[(BASE) + 18] = (int)(S##18 & IMASK) + (C0);                          \
    pi[(BASE) + 19] = (int)(S##19 & IMASK) + (C0);                          \
  } while (0)

// R30: packed dual-fma using NATIVE vector halves (sub-register aliasing,
// no operand-marshalling movs). QV is f32x4; halves via shufflevector.
#define PK2V(QV, WLO, WHI, ACC0, ACC1)                                      \
  do {                                                                      \
    f32x2 qlo_ = __builtin_shufflevector((QV), (QV), 0, 1);                 \
    f32x2 qhi_ = __builtin_shufflevector((QV), (QV), 2, 3);                 \
    ACC0 = __builtin_elementwise_fma(qlo_, (WLO), ACC0);                    \
    ACC1 = __builtin_elementwise_fma(qhi_, (WHI), ACC1);                    \
  } while (0)

// legacy float4 variant (fallback kernels)
#define PK2(QF4, WLO, WHI, ACC0, ACC1)                             \
  do {                                                             \
    f32x2 qlo_ = {(QF4).x, (QF4).y};                               \
    f32x2 qhi_ = {(QF4).z, (QF4).w};                               \
    ACC0 = __builtin_elementwise_fma(qlo_, (WLO), ACC0);           \
    ACC1 = __builtin_elementwise_fma(qhi_, (WHI), ACC1);           \
  } while (0)

// Q=2 partial (R22 unroll-2), stores RAW packed u32 lists (R25).
// R30: all fragments are native f32x4; halves alias sub-registers.
template <int P>
__global__ __launch_bounds__(256)
__attribute__((amdgpu_waves_per_eu(2, 2)))
void knn_partial2_kernel(
    const float* __restrict__ x, const float* __restrict__ x2,
    int* __restrict__ pi) {
  constexpr int IB = (P == 8) ? 10 : (P == 4) ? 11 : 12;
  constexpr unsigned IMASK = (1u << IB) - 1u;
  constexpr unsigned QMASK = ~IMASK;

  __shared__ unsigned lbufA[FB * 256];
  __shared__ unsigned lbufB[FB * 256];

  const int tid      = threadIdx.x;
  const int rb       = blockIdx.x / P;
  const int chunk    = blockIdx.x % P;
  const int base_row = rb * 512;
  const int b        = base_row >> 13;
  const int rowA     = base_row + tid;
  const int rowB     = rowA + 256;
  const int jA       = rowA & (MM - 1);
  const int jB       = jA + 256;

  const float* __restrict__ xb  = x + (size_t)b * MM * DD;
  const float* __restrict__ x2b = x2 + b * MM;

  const f32x4* qpA = (const f32x4*)(xb + (size_t)jA * DD);
  const f32x4* qpB = (const f32x4*)(xb + (size_t)jB * DD);
  f32x4 qa0 = qpA[0],  qa1 = qpA[1],  qa2 = qpA[2],  qa3 = qpA[3];
  f32x4 qa4 = qpA[4],  qa5 = qpA[5],  qa6 = qpA[6],  qa7 = qpA[7];
  f32x4 qa8 = qpA[8],  qa9 = qpA[9],  qa10 = qpA[10], qa11 = qpA[11];
  f32x4 qa12 = qpA[12], qa13 = qpA[13], qa14 = qpA[14], qa15 = qpA[15];
  f32x4 qb0 = qpB[0],  qb1 = qpB[1],  qb2 = qpB[2],  qb3 = qpB[3];
  f32x4 qb4 = qpB[4],  qb5 = qpB[5],  qb6 = qpB[6],  qb7 = qpB[7];
  f32x4 qb8 = qpB[8],  qb9 = qpB[9],  qb10 = qpB[10], qb11 = qpB[11];
  f32x4 qb12 = qpB[12], qb13 = qpB[13], qb14 = qpB[14], qb15 = qpB[15];

  PDECL20(sa)
  PDECL20(sb)
  int cA = 0, cB = 0;

#define FLUSHQ()                                                   \
  do {                                                             \
    _Pragma("unroll")                                              \
    for (int t_ = 0; t_ < FB; ++t_) {                              \
      if (t_ < cA) {                                               \
        unsigned pk_ = lbufA[t_ * 256 + tid];                      \
        sa19 = min(sa19, pk_);                                     \
        PBUBBLE20(sa);                                             \
      }                                                            \
      if (t_ < cB) {                                               \
        unsigned pk_ = lbufB[t_ * 256 + tid];                      \
        sb19 = min(sb19, pk_);                                     \
        PBUBBLE20(sb);                                             \
      }                                                            \
    }                                                              \
    cA = 0;                                                        \
    cB = 0;                                                        \
  } while (0)

  const int C  = MM / P;
  const int c0 = chunk * C;

#pragma unroll 1
  for (int c = c0; c < c0 + C; c += 2) {
    const f32x4* cp0 = (const f32x4*)(xb + (size_t)c * DD);        // unif
    const f32x4* cp1 = (const f32x4*)(xb + (size_t)(c + 1) * DD);  // unif
    float x2c0 = x2b[c];
    float x2c1 = x2b[c + 1];

    f32x4 u0 = cp0[0],  u1 = cp0[1],  u2 = cp0[2],  u3 = cp0[3];
    f32x4 u4 = cp0[4],  u5 = cp0[5],  u6 = cp0[6],  u7 = cp0[7];
    f32x4 u8 = cp0[8],  u9 = cp0[9],  u10 = cp0[10], u11 = cp0[11];
    f32x4 u12 = cp0[12], u13 = cp0[13], u14 = cp0[14], u15 = cp0[15];
    f32x4 t0 = cp1[0],  t1 = cp1[1],  t2 = cp1[2],  t3 = cp1[3];
    f32x4 t4 = cp1[4],  t5 = cp1[5],  t6 = cp1[6],  t7 = cp1[7];
    f32x4 t8 = cp1[8],  t9 = cp1[9],  t10 = cp1[10], t11 = cp1[11];
    f32x4 t12 = cp1[12], t13 = cp1[13], t14 = cp1[14], t15 = cp1[15];

    // ---- candidate c ----
    {
      f32x2 aA0 = {0.f, 0.f}, aA1 = {0.f, 0.f};
      f32x2 aB0 = {0.f, 0.f}, aB1 = {0.f, 0.f};
      {
        f32x2 wlo, whi;
#define USEW(W)                                                \
  wlo = __builtin_shufflevector((W), (W), 0, 1);               \
  whi = __builtin_shufflevector((W), (W), 2, 3)
        USEW(u0);  PK2V(qa0,  wlo, whi, aA0, aA1); PK2V(qb0,  wlo, whi, aB0, aB1);
        USEW(u1);  PK2V(qa1,  wlo, whi, aA0, aA1); PK2V(qb1,  wlo, whi, aB0, aB1);
        USEW(u2);  PK2V(qa2,  wlo, whi, aA0, aA1); PK2V(qb2,  wlo, whi, aB0, aB1);
        USEW(u3);  PK2V(qa3,  wlo, whi, aA0, aA1); PK2V(qb3,  wlo, whi, aB0, aB1);
        USEW(u4);  PK2V(qa4,  wlo, whi, aA0, aA1); PK2V(qb4,  wlo, whi, aB0, aB1);
        USEW(u5);  PK2V(qa5,  wlo, whi, aA0, aA1); PK2V(qb5,  wlo, whi, aB0, aB1);
        USEW(u6);  PK2V(qa6,  wlo, whi, aA0, aA1); PK2V(qb6,  wlo, whi, aB0, aB1);
        USEW(u7);  PK2V(qa7,  wlo, whi, aA0, aA1); PK2V(qb7,  wlo, whi, aB0, aB1);
        USEW(u8);  PK2V(qa8,  wlo, whi, aA0, aA1); PK2V(qb8,  wlo, whi, aB0, aB1);
        USEW(u9);  PK2V(qa9,  wlo, whi, aA0, aA1); PK2V(qb9,  wlo, whi, aB0, aB1);
        USEW(u10); PK2V(qa10, wlo, whi, aA0, aA1); PK2V(qb10, wlo, whi, aB0, aB1);
        USEW(u11); PK2V(qa11, wlo, whi, aA0, aA1); PK2V(qb11, wlo, whi, aB0, aB1);
        USEW(u12); PK2V(qa12, wlo, whi, aA0, aA1); PK2V(qb12, wlo, whi, aB0, aB1);
        USEW(u13); PK2V(qa13, wlo, whi, aA0, aA1); PK2V(qb13, wlo, whi, aB0, aB1);
        USEW(u14); PK2V(qa14, wlo, whi, aA0, aA1); PK2V(qb14, wlo, whi, aB0, aB1);
        USEW(u15); PK2V(qa15, wlo, whi, aA0, aA1); PK2V(qb15, wlo, whi, aB0, aB1);
      }
      f32x2 rA = aA0 + aA1;
      f32x2 rB = aB0 + aB1;
      float dotA = rA.x + rA.y;
      float dotB = rB.x + rB.y;
      float keyA = fmaf(-2.f, dotA, x2c0);
      float keyB = fmaf(-2.f, dotB, x2c0);

      int kiA = __float_as_int(keyA);
      unsigned monoA = (unsigned)kiA ^ ((unsigned)(kiA >> 31) | 0x80000000u);
      unsigned pkA = (monoA & QMASK) | (unsigned)(c - c0);
      if (pkA < sa19) { lbufA[cA * 256 + tid] = pkA; ++cA; }

      int kiB = __float_as_int(keyB);
      unsigned monoB = (unsigned)kiB ^ ((unsigned)(kiB >> 31) | 0x80000000u);
      unsigned pkB = (monoB & QMASK) | (unsigned)(c - c0);
      if (pkB < sb19) { lbufB[cB * 256 + tid] = pkB; ++cB; }
    }

    // ---- candidate c+1 ----
    {
      f32x2 aA0 = {0.f, 0.f}, aA1 = {0.f, 0.f};
      f32x2 aB0 = {0.f, 0.f}, aB1 = {0.f, 0.f};
      {
        f32x2 wlo, whi;
        USEW(t0);  PK2V(qa0,  wlo, whi, aA0, aA1); PK2V(qb0,  wlo, whi, aB0, aB1);
        USEW(t1);  PK2V(qa1,  wlo, whi, aA0, aA1); PK2V(qb1,  wlo, whi, aB0, aB1);
        USEW(t2);  PK2V(qa2,  wlo, whi, aA0, aA1); PK2V(qb2,  wlo, whi, aB0, aB1);
        USEW(t3);  PK2V(qa3,  wlo, whi, aA0, aA1); PK2V(qb3,  wlo, whi, aB0, aB1);
        USEW(t4);  PK2V(qa4,  wlo, whi, aA0, aA1); PK2V(qb4,  wlo, whi, aB0, aB1);
        USEW(t5);  PK2V(qa5,  wlo, whi, aA0, aA1); PK2V(qb5,  wlo, whi, aB0, aB1);
        USEW(t6);  PK2V(qa6,  wlo, whi, aA0, aA1); PK2V(qb6,  wlo, whi, aB0, aB1);
        USEW(t7);  PK2V(qa7,  wlo, whi, aA0, aA1); PK2V(qb7,  wlo, whi, aB0, aB1);
        USEW(t8);  PK2V(qa8,  wlo, whi, aA0, aA1); PK2V(qb8,  wlo, whi, aB0, aB1);
        USEW(t9);  PK2V(qa9,  wlo, whi, aA0, aA1); PK2V(qb9,  wlo, whi, aB0, aB1);
        USEW(t10); PK2V(qa10, wlo, whi, aA0, aA1); PK2V(qb10, wlo, whi, aB0, aB1);
        USEW(t11); PK2V(qa11, wlo, whi, aA0, aA1); PK2V(qb11, wlo, whi, aB0, aB1);
        USEW(t12); PK2V(qa12, wlo, whi, aA0, aA1); PK2V(qb12, wlo, whi, aB0, aB1);
        USEW(t13); PK2V(qa13, wlo, whi, aA0, aA1); PK2V(qb13, wlo, whi, aB0, aB1);
        USEW(t14); PK2V(qa14, wlo, whi, aA0, aA1); PK2V(qb14, wlo, whi, aB0, aB1);
        USEW(t15); PK2V(qa15, wlo, whi, aA0, aA1); PK2V(qb15, wlo, whi, aB0, aB1);
#undef USEW
      }
      f32x2 rA = aA0 + aA1;
      f32x2 rB = aB0 + aB1;
      float dotA = rA.x + rA.y;
      float dotB = rB.x + rB.y;
      float keyA = fmaf(-2.f, dotA, x2c1);
      float keyB = fmaf(-2.f, dotB, x2c1);

      int kiA = __float_as_int(keyA);
      unsigned monoA = (unsigned)kiA ^ ((unsigned)(kiA >> 31) | 0x80000000u);
      unsigned pkA = (monoA & QMASK) | (unsigned)(c + 1 - c0);
      if (pkA < sa19) { lbufA[cA * 256 + tid] = pkA; ++cA; }

      int kiB = __float_as_int(keyB);
      unsigned monoB = (unsigned)kiB ^ ((unsigned)(kiB >> 31) | 0x80000000u);
      unsigned pkB = (monoB & QMASK) | (unsigned)(c + 1 - c0);
      if (pkB < sb19) { lbufB[cB * 256 + tid] = pkB; ++cB; }
    }

    if (__any((cA | cB) >= FB - 2)) FLUSHQ();
  }

  FLUSHQ();  // final drain
#undef FLUSHQ

  size_t baseA = ((size_t)rowA * P + chunk) * TK;
  size_t baseB = ((size_t)rowB * P + chunk) * TK;
  PSTORE20RAW(baseA, sa);
  PSTORE20RAW(baseB, sb);
}

// Q=1 packed partial (LDS path) — workspace fallback only (stores idx).
template <int P>
__global__ __launch_bounds__(256)
__attribute__((amdgpu_waves_per_eu(2, 2)))
void knn_partial_q1_kernel(
    const float* __restrict__ x, const float* __restrict__ x2,
    int* __restrict__ pi) {
  constexpr int IB = (P == 8) ? 10 : (P == 4) ? 11 : (P == 2) ? 12 : 13;
  constexpr unsigned IMASK = (1u << IB) - 1u;
  constexpr unsigned QMASK = ~IMASK;

  __shared__ float tile[TILE * DD];
  __shared__ float x2t[TILE];

  const int tid   = threadIdx.x;
  const int rb    = blockIdx.x / P;
  const int chunk = blockIdx.x % P;
  const int b     = rb >> 5;
  const int row   = rb * 256 + tid;
  const int j     = row - b * MM;

  const float* __restrict__ xb  = x + (size_t)b * MM * DD;
  const float* __restrict__ x2b = x2 + b * MM;

  const float4* qp = (const float4*)(xb + (size_t)j * DD);
  float4 q0 = qp[0],  q1 = qp[1],  q2 = qp[2],  q3 = qp[3];
  float4 q4 = qp[4],  q5 = qp[5],  q6 = qp[6],  q7 = qp[7];
  float4 q8 = qp[8],  q9 = qp[9],  q10 = qp[10], q11 = qp[11];
  float4 q12 = qp[12], q13 = qp[13], q14 = qp[14], q15 = qp[15];

  PDECL20(s)

  const int C  = MM / P;
  const int c0 = chunk * C;

  for (int ts = c0; ts < c0 + C; ts += TILE) {
    __syncthreads();
    {
      const float4* gsrc = (const float4*)(xb + (size_t)ts * DD);
      float4* lds4 = (float4*)tile;
#pragma unroll
      for (int u = 0; u < 4; ++u) lds4[tid + 256 * u] = gsrc[tid + 256 * u];
      if (tid < TILE / 4)
        ((float4*)x2t)[tid] = ((const float4*)(x2b + ts))[tid];
    }
    __syncthreads();

#pragma unroll 2
    for (int t = 0; t < TILE; ++t) {
      const float4* cp = (const float4*)(tile + t * DD);
      f32x2 a0 = {0.f, 0.f}, a1 = {0.f, 0.f};
      {
        float4 w;
        f32x2 wlo, whi;
#define LOADW(I)  w = cp[I]; wlo = (f32x2){w.x, w.y}; whi = (f32x2){w.z, w.w}
        LOADW(0);  PK2(q0,  wlo, whi, a0, a1);
        LOADW(1);  PK2(q1,  wlo, whi, a0, a1);
        LOADW(2);  PK2(q2,  wlo, whi, a0, a1);
        LOADW(3);  PK2(q3,  wlo, whi, a0, a1);
        LOADW(4);  PK2(q4,  wlo, whi, a0, a1);
        LOADW(5);  PK2(q5,  wlo, whi, a0, a1);
        LOADW(6);  PK2(q6,  wlo, whi, a0, a1);
        LOADW(7);  PK2(q7,  wlo, whi, a0, a1);
        LOADW(8);  PK2(q8,  wlo, whi, a0, a1);
        LOADW(9);  PK2(q9,  wlo, whi, a0, a1);
        LOADW(10); PK2(q10, wlo, whi, a0, a1);
        LOADW(11); PK2(q11, wlo, whi, a0, a1);
        LOADW(12); PK2(q12, wlo, whi, a0, a1);
        LOADW(13); PK2(q13, wlo, whi, a0, a1);
        LOADW(14); PK2(q14, wlo, whi, a0, a1);
        LOADW(15); PK2(q15, wlo, whi, a0, a1);
#undef LOADW
      }
      f32x2 rr = a0 + a1;
      float dot = rr.x + rr.y;
      float key = fmaf(-2.f, dot, x2t[t]);

      int ki = __float_as_int(key);
      unsigned mono = (unsigned)ki ^ ((unsigned)(ki >> 31) | 0x80000000u);
      unsigned pk = (mono & QMASK) | (unsigned)(ts - c0 + t);
      s19 = min(s19, pk);
      PBUBBLE20(s);
    }
  }

  size_t base = ((size_t)row * P + chunk) * TK;
  PSTORE20(base, s, c0);
}

// FROZEN-numerics einsum block: per-product rounding then reversed adds.
#define EBLK(QA, QB, QC, QD, W0, W1, W2, W3)                                  \
  do {                                                                        \
    v0 = (QA).x * (W0).x +                                                    \
         ((QB).x * (W1).x + ((QC).x * (W2).x + ((QD).x * (W3).x + v0)));      \
    v1 = (QA).y * (W0).y +                                                    \
         ((QB).y * (W1).y + ((QC).y * (W2).y + ((QD).y * (W3).y + v1)));      \
    v2 = (QA).z * (W0).z +                                                    \
         ((QB).z * (W1).z + ((QC).z * (W2).z + ((QD).z * (W3).z + v2)));      \
    v3 = (QA).w * (W0).w +                                                    \
         ((QB).w * (W1).w + ((QC).w * (W2).w + ((QD).w * (W3).w + v3)));      \
  } while (0)

// Lexicographic (d2, idx) compare-swap (strict: stable).
#define LBSTEP(dA, iA, dB, iB)                                     \
  do {                                                             \
    bool s_ = ((dB) < (dA)) || ((dB) == (dA) && (iB) < (iA));      \
    float tl_ = s_ ? (dB) : (dA);                                  \
    float th_ = s_ ? (dA) : (dB);                                  \
    int   jl_ = s_ ? (iB) : (iA);                                  \
    int   jh_ = s_ ? (iA) : (iB);                                  \
    (dA) = tl_; (dB) = th_; (iA) = jl_; (iB) = jh_;                \
  } while (0)

// Exact rescore of one candidate + insertion (shared by rescore kernels).
#define RESCORE_ONE(C_)                                                     \
  {                                                                         \
    int c = (C_);                                                           \
    const float4* pp = (const float4*)(xb + (size_t)c * DD);                \
    float v0 = 0.f, v1 = 0.f, v2 = 0.f, v3 = 0.f;                           \
    {                                                                       \
      float4 w0 = pp[0], w1 = pp[1], w2 = pp[2], w3 = pp[3];                \
      EBLK(q0, q1, q2, q3, w0, w1, w2, w3);                                 \
    }                                                                       \
    {                                                                       \
      float4 w0 = pp[4], w1 = pp[5], w2 = pp[6], w3 = pp[7];                \
      EBLK(q4, q5, q6, q7, w0, w1, w2, w3);                                 \
    }                                                                       \
    {                                                                       \
      float4 w0 = pp[8], w1 = pp[9], w2 = pp[10], w3 = pp[11];              \
      EBLK(q8, q9, q10, q11, w0, w1, w2, w3);                               \
    }                                                                       \
    {                                                                       \
      float4 w0 = pp[12], w1 = pp[13], w2 = pp[14], w3 = pp[15];            \
      EBLK(q12, q13, q14, q15, w0, w1, w2, w3);                             \
    }                                                                       \
    float dotf = (v0 + v1) + (v2 + v3);                                     \
    float s  = x2j + x2[b * MM + c];                                        \
    float tm = 2.0f * dotf;                                                 \
    float d2 = s - tm;                                                      \
    bool lt = (d2 < e15) || (d2 == e15 && c < n15);                         \
    e15 = lt ? d2 : e15;                                                    \
    n15 = lt ? c : n15;                                                     \
    LBSTEP(e14, n14, e15, n15); LBSTEP(e13, n13, e14, n14);                 \
    LBSTEP(e12, n12, e13, n13); LBSTEP(e11, n11, e12, n12);                 \
    LBSTEP(e10, n10, e11, n11); LBSTEP(e9,  n9,  e10, n10);                 \
    LBSTEP(e8,  n8,  e9,  n9);  LBSTEP(e7,  n7,  e8,  n8);                  \
    LBSTEP(e6,  n6,  e7,  n7);  LBSTEP(e5,  n5,  e6,  n6);                  \
    LBSTEP(e4,  n4,  e5,  n5);  LBSTEP(e3,  n3,  e4,  n4);                  \
    LBSTEP(e2,  n2,  e3,  n3);  LBSTEP(e1,  n1,  e2,  n2);                  \
    LBSTEP(e0,  n0,  e1,  n1);                                              \
  }

// Publish per-sub sorted list + 8-way final merge (shared epilogue).
#define PUBLISH_AND_MERGE8()                                                \
  {                                                                         \
    ls[sub][0][lane]  = make_uint2(MONO(e0),  (unsigned)n0);                \
    ls[sub][1][lane]  = make_uint2(MONO(e1),  (unsigned)n1);                \
    ls[sub][2][lane]  = make_uint2(MONO(e2),  (unsigned)n2);                \
    ls[sub][3][lane]  = make_uint2(MONO(e3),  (unsigned)n3);                \
    ls[sub][4][lane]  = make_uint2(MONO(e4),  (unsigned)n4);                \
    ls[sub][5][lane]  = make_uint2(MONO(e5),  (unsigned)n5);                \
    ls[sub][6][lane]  = make_uint2(MONO(e6),  (unsigned)n6);                \
    ls[sub][7][lane]  = make_uint2(MONO(e7),  (unsigned)n7);                \
    ls[sub][8][lane]  = make_uint2(MONO(e8),  (unsigned)n8);                \
    ls[sub][9][lane]  = make_uint2(MONO(e9),  (unsigned)n9);                \
    ls[sub][10][lane] = make_uint2(MONO(e10), (unsigned)n10);               \
    ls[sub][11][lane] = make_uint2(MONO(e11), (unsigned)n11);               \
    ls[sub][12][lane] = make_uint2(MONO(e12), (unsigned)n12);               \
    ls[sub][13][lane] = make_uint2(MONO(e13), (unsigned)n13);               \
    ls[sub][14][lane] = make_uint2(MONO(e14), (unsigned)n14);               \
    ls[sub][15][lane] = make_uint2(MONO(e15), (unsigned)n15);               \
    __syncthreads();                                                        \
    if (sub == 0) {                                                         \
      uint2 c0v = ls[0][0][lane], c1v = ls[1][0][lane];                     \
      uint2 c2v = ls[2][0][lane], c3v = ls[3][0][lane];                     \
      uint2 c4v = ls[4][0][lane], c5v = ls[5][0][lane];                     \
      uint2 c6v = ls[6][0][lane], c7v = ls[7][0][lane];                     \
      int h0 = 1, h1 = 1, h2 = 1, h3 = 1, h4 = 1, h5 = 1, h6 = 1, h7 = 1;   \
      const uint2 SENT = make_uint2(0xFFFFFFFFu, 0x7FFFFFFFu);              \
      for (int out = 0; out < KK; ++out) {                                  \
        bool l01 = LESS2(c0v, c1v);                                         \
        uint2 m01 = l01 ? c0v : c1v; int w01 = l01 ? 0 : 1;                 \
        bool l23 = LESS2(c2v, c3v);                                         \
        uint2 m23 = l23 ? c2v : c3v; int w23 = l23 ? 2 : 3;                 \
        bool l45 = LESS2(c4v, c5v);                                         \
        uint2 m45 = l45 ? c4v : c5v; int w45 = l45 ? 4 : 5;                 \
        bool l67 = LESS2(c6v, c7v);                                         \
        uint2 m67 = l67 ? c6v : c7v; int w67 = l67 ? 6 : 7;                 \
        bool la = LESS2(m01, m23);                                          \
        uint2 ma = la ? m01 : m23; int wa = la ? w01 : w23;                 \
        bool lb = LESS2(m45, m67);                                          \
        uint2 mb = lb ? m45 : m67; int wb = lb ? w45 : w67;                 \
        bool lf = LESS2(ma, mb);                                            \
        uint2 mv = lf ? ma : mb; int wf = lf ? wa : wb;                     \
        src[(size_t)r * KK + out] = b * MM + (int)mv.y;                     \
        dst[(size_t)r * KK + out] = r;                                      \
        if (wf == 0)      { c0v = (h0 < 16) ? ls[0][h0][lane] : SENT; ++h0; }\
        else if (wf == 1) { c1v = (h1 < 16) ? ls[1][h1][lane] : SENT; ++h1; }\
        else if (wf == 2) { c2v = (h2 < 16) ? ls[2][h2][lane] : SENT; ++h2; }\
        else if (wf == 3) { c3v = (h3 < 16) ? ls[3][h3][lane] : SENT; ++h3; }\
        else if (wf == 4) { c4v = (h4 < 16) ? ls[4][h4][lane] : SENT; ++h4; }\
        else if (wf == 5) { c5v = (h5 < 16) ? ls[5][h5][lane] : SENT; ++h5; }\
        else if (wf == 6) { c6v = (h6 < 16) ? ls[6][h6][lane] : SENT; ++h6; }\
        else              { c7v = (h7 < 16) ? ls[7][h7][lane] : SENT; ++h7; }\
      }                                                                     \
    }                                                                       \
  }

#define MONO(F) ({ int k_ = __float_as_int(F); \
                   (unsigned)k_ ^ ((unsigned)(k_ >> 31) | 0x80000000u); })
#define LESS2(A, B) ((A).x < (B).x || ((A).x == (B).x && (A).y < (B).y))

// R25 filtered rescore (P=8/4 path): 8 sorted chunk-lists, 8 subs.
template <int P>
__global__ __launch_bounds__(256) void knn_rescore8f_kernel(
    const float* __restrict__ x, const float* __restrict__ x2,
    const int* __restrict__ pi,
    int* __restrict__ src, int* __restrict__ dst) {
#pragma clang fp contract(off)
  constexpr int IB = (P == 8) ? 10 : 11;
  constexpr unsigned IMASK = (1u << IB) - 1u;
  constexpr unsigned QMASK = ~IMASK;
  constexpr int CAND = P * TK;
  constexpr int LPT  = CAND / 8;
  constexpr int CC   = MM / P;

  __shared__ unsigned lk[8][LPT][32];
  __shared__ uint2 ls[8][16][32];
  __shared__ unsigned thr[32];

  const int tid  = threadIdx.x;
  const int lane = tid & 31;
  const int sub  = tid >> 5;
  const int r    = blockIdx.x * 32 + lane;
  const int b    = r >> 13;
  const int j    = r & (MM - 1);
  const float* __restrict__ xb = x + (size_t)b * MM * DD;
  const float x2j = x2[r];

  const float4* qp = (const float4*)(xb + (size_t)j * DD);
  float4 q0 = qp[0],  q1 = qp[1],  q2 = qp[2],  q3 = qp[3];
  float4 q4 = qp[4],  q5 = qp[5],  q6 = qp[6],  q7 = qp[7];
  float4 q8 = qp[8],  q9 = qp[9],  q10 = qp[10], q11 = qp[11];
  float4 q12 = qp[12], q13 = qp[13], q14 = qp[14], q15 = qp[15];

  {
    const uint2* pp2 =
        (const uint2*)((const unsigned*)pi + (size_t)r * CAND + sub * LPT);
#pragma unroll
    for (int i = 0; i < LPT / 2; ++i) {
      uint2 v = pp2[i];
      lk[sub][2 * i][lane]     = v.x;
      lk[sub][2 * i + 1][lane] = v.y;
    }
  }
  __syncthreads();

  if (sub == 0) {
    unsigned c0v = lk[0][0][lane], c1v = lk[1][0][lane];
    unsigned c2v = lk[2][0][lane], c3v = lk[3][0][lane];
    unsigned c4v = lk[4][0][lane], c5v = lk[5][0][lane];
    unsigned c6v = lk[6][0][lane], c7v = lk[7][0][lane];
    int h0 = 1, h1 = 1, h2 = 1, h3 = 1, h4 = 1, h5 = 1, h6 = 1, h7 = 1;
    unsigned P16 = 0;
#pragma unroll 1
    for (int out = 0; out < 16; ++out) {
      bool l01 = c0v < c1v; unsigned m01 = l01 ? c0v : c1v; int w01 = l01 ? 0 : 1;
      bool l23 = c2v < c3v; unsigned m23 = l23 ? c2v : c3v; int w23 = l23 ? 2 : 3;
      bool l45 = c4v < c5v; unsigned m45 = l45 ? c4v : c5v; int w45 = l45 ? 4 : 5;
      bool l67 = c6v < c7v; unsigned m67 = l67 ? c6v : c7v; int w67 = l67 ? 6 : 7;
      bool la = m01 < m23; unsigned ma = la ? m01 : m23; int wa = la ? w01 : w23;
      bool lb = m45 < m67; unsigned mb = lb ? m45 : m67; int wb = lb ? w45 : w67;
      bool lf = ma < mb; unsigned mv = lf ? ma : mb; int wf = lf ? wa : wb;
      P16 = mv;
      if (wf == 0)      { c0v = (h0 < LPT) ? lk[0][h0][lane] : 0xFFFFFFFFu; ++h0; }
      else if (wf == 1) { c1v = (h1 < LPT) ? lk[1][h1][lane] : 0xFFFFFFFFu; ++h1; }
      else if (wf == 2) { c2v = (h2 < LPT) ? lk[2][h2][lane] : 0xFFFFFFFFu; ++h2; }
      else if (wf == 3) { c3v = (h3 < LPT) ? lk[3][h3][lane] : 0xFFFFFFFFu; ++h3; }
      else if (wf == 4) { c4v = (h4 < LPT) ? lk[4][h4][lane] : 0xFFFFFFFFu; ++h4; }
      else if (wf == 5) { c5v = (h5 < LPT) ? lk[5][h5][lane] : 0xFFFFFFFFu; ++h5; }
      else if (wf == 6) { c6v = (h6 < LPT) ? lk[6][h6][lane] : 0xFFFFFFFFu; ++h6; }
      else              { c7v = (h7 < LPT) ? lk[7][h7][lane] : 0xFFFFFFFFu; ++h7; }
    }
    thr[lane] = ((P16 & QMASK) + (1u << IB)) | IMASK;
  }
  __syncthreads();
  const unsigned T = thr[lane];

  const float INF = __builtin_inff();
  float e0 = INF, e1 = INF, e2 = INF, e3 = INF, e4 = INF, e5 = INF,
        e6 = INF, e7 = INF, e8 = INF, e9 = INF, e10 = INF, e11 = INF,
        e12 = INF, e13 = INF, e14 = INF, e15 = INF;
  int n0 = 0x7fffffff, n1 = 0x7fffffff, n2 = 0x7fffffff, n3 = 0x7fffffff,
      n4 = 0x7fffffff, n5 = 0x7fffffff, n6 = 0x7fffffff, n7 = 0x7fffffff,
      n8 = 0x7fffffff, n9 = 0x7fffffff, n10 = 0x7fffffff, n11 = 0x7fffffff,
      n12 = 0x7fffffff, n13 = 0x7fffffff, n14 = 0x7fffffff, n15 = 0x7fffffff;

#pragma unroll 1
  for (int t = 0; t < LPT; ++t) {
    unsigned pk = lk[sub][t][lane];
    if (__all((int)(pk > T))) break;
    if (pk <= T) {
      int ent = sub * LPT + t;
      int chunk = ent / TK;
      RESCORE_ONE((int)(pk & IMASK) + chunk * CC)
    }
  }

  PUBLISH_AND_MERGE8()
}

// Index-based rescore (fallback path, pi = plain indices).
template <int P>
__global__ __launch_bounds__(256) void knn_rescore8_kernel(
    const float* __restrict__ x, const float* __restrict__ x2,
    const int* __restrict__ pi,
    int* __restrict__ src, int* __restrict__ dst) {
#pragma clang fp contract(off)
  constexpr int CAND = P * TK;
  constexpr int LPT  = CAND / 8;
  __shared__ uint2 ls[8][16][32];

  const int tid  = threadIdx.x;
  const int lane = tid & 31;
  const int sub  = tid >> 5;
  const int r    = blockIdx.x * 32 + lane;
  const int b    = r >> 13;
  const int j    = r & (MM - 1);
  const float* __restrict__ xb = x + (size_t)b * MM * DD;
  const float x2j = x2[r];

  const float4* qp = (const float4*)(xb + (size_t)j * DD);
  float4 q0 = qp[0],  q1 = qp[1],  q2 = qp[2],  q3 = qp[3];
  float4 q4 = qp[4],  q5 = qp[5],  q6 = qp[6],  q7 = qp[7];
  float4 q8 = qp[8],  q9 = qp[9],  q10 = qp[10], q11 = qp[11];
  float4 q12 = qp[12], q13 = qp[13], q14 = qp[14], q15 = qp[15];

  const float INF = __builtin_inff();
  float e0 = INF, e1 = INF, e2 = INF, e3 = INF, e4 = INF, e5 = INF,
        e6 = INF, e7 = INF, e8 = INF, e9 = INF, e10 = INF, e11 = INF,
        e12 = INF, e13 = INF, e14 = INF, e15 = INF;
  int n0 = 0x7fffffff, n1 = 0x7fffffff, n2 = 0x7fffffff, n3 = 0x7fffffff,
      n4 = 0x7fffffff, n5 = 0x7fffffff, n6 = 0x7fffffff, n7 = 0x7fffffff,
      n8 = 0x7fffffff, n9 = 0x7fffffff, n10 = 0x7fffffff, n11 = 0x7fffffff,
      n12 = 0x7fffffff, n13 = 0x7fffffff, n14 = 0x7fffffff, n15 = 0x7fffffff;

  size_t base = (size_t)r * CAND + (size_t)sub * LPT;

  for (int t = 0; t < LPT; ++t) {
    RESCORE_ONE(pi[base + t])
  }

  PUBLISH_AND_MERGE8()
}

extern "C" void kernel_launch(void* const* d_in, const int* in_sizes, int n_in,
                              void* d_out, int out_size, void* d_ws, size_t ws_size,
                              hipStream_t stream) {
  const float* x = (const float*)d_in[0];
  int* out = (int*)d_out;

  char* ws = (char*)d_ws;
  float* x2 = (float*)ws;
  int*   pi = (int*)(ws + (size_t)NROWS * sizeof(float));
  int* src = out;
  int* dst = out + (size_t)NROWS * KK;

  auto need = [](int P) {
    return (size_t)NROWS * sizeof(float) +
           (size_t)NROWS * P * TK * sizeof(int);
  };

  norms_np_kernel<<<NROWS / 256, 256, 0, stream>>>(x, x2);

  if (ws_size >= need(8)) {
    // R30: R25 pipeline with native-vector operand aliasing.
    knn_partial2_kernel<8><<<(NROWS / 512) * 8, 256, 0, stream>>>(x, x2, pi);
    knn_rescore8f_kernel<8><<<NROWS / 32, 256, 0, stream>>>(x, x2, pi, src, dst);
  } else if (ws_size >= need(4)) {
    knn_partial2_kernel<4><<<(NROWS / 512) * 4, 256, 0, stream>>>(x, x2, pi);
    knn_rescore8f_kernel<4><<<NROWS / 32, 256, 0, stream>>>(x, x2, pi, src, dst);
  } else if (ws_size >= need(2)) {
    knn_partial_q1_kernel<2><<<(NROWS / 256) * 2, 256, 0, stream>>>(x, x2, pi);
    knn_rescore8_kernel<2><<<NROWS / 32, 256, 0, stream>>>(x, x2, pi, src, dst);
  } else {
    knn_partial_q1_kernel<1><<<(NROWS / 256) * 1, 256, 0, stream>>>(x, x2, pi);
    knn_rescore8_kernel<1><<<NROWS / 32, 256, 0, stream>>>(x, x2, pi, src, dst);
  }
}